// Round 1
// baseline (363.529 us; speedup 1.0000x reference)
//
#include <hip/hip_runtime.h>
#include <math.h>

#define BB    8
#define TDIM  64
#define NN    128
#define DD    128
#define TTOUT 62      // T-2
#define W3    384     // 3*N
#define PR    132     // padded row stride for 128-wide LDS tiles
#define PP    33      // padded row stride for P (32-wide)

__device__ __forceinline__ float sigf(float x){ return 1.0f/(1.0f+__expf(-x)); }

// K1: rscale[b,t,n] = 1 / max(||feat[b,t,n,:]*sigmoid(w)||, 1e-12)
__global__ void k_rscale(const float* __restrict__ feat, const float* __restrict__ w,
                         float* __restrict__ rscale){
  int row  = blockIdx.x*4 + (threadIdx.x>>6);   // [0, B*T*N)
  int lane = threadIdx.x & 63;
  float2 f  = *(const float2*)(feat + (size_t)row*DD + lane*2);
  float2 wv = *(const float2*)(w + lane*2);
  float v0 = f.x * sigf(wv.x);
  float v1 = f.y * sigf(wv.y);
  float ss = v0*v0 + v1*v1;
  #pragma unroll
  for(int k=32;k>=1;k>>=1) ss += __shfl_xor(ss, k);
  if(lane==0) rscale[row] = 1.0f / fmaxf(sqrtf(ss), 1e-12f);
}

// K2: ssum[b,t,d] = sum_n wf[b,t,n,d] = sig(w[d]) * sum_n feat[b,t,n,d]*rscale[b,t,n]
__global__ void k_ssum(const float* __restrict__ feat, const float* __restrict__ w,
                       const float* __restrict__ rscale, float* __restrict__ ssum){
  int bt = blockIdx.x;        // [0, B*T)
  int d  = threadIdx.x;       // 128
  const float* fp = feat + (size_t)bt*NN*DD + d;
  const float* rp = rscale + bt*NN;
  float acc = 0.f;
  #pragma unroll 4
  for(int n=0;n<NN;n++) acc += fp[(size_t)n*DD] * rp[n];
  ssum[bt*DD + d] = acc * sigf(w[d]);
}

// K3: dis[b,tt,j] = deg>0 ? rsqrt(max(deg,1e-38)) : 0, deg = G[j]·s3
__global__ void k_dis(const float* __restrict__ feat, const float* __restrict__ w,
                      const float* __restrict__ rscale, const float* __restrict__ ssum,
                      float* __restrict__ dis){
  __shared__ float s3[DD];
  __shared__ float sg[DD];
  int bt2 = blockIdx.x;                  // [0, B*(T-2))
  int b = bt2 / TTOUT, tt = bt2 % TTOUT;
  int tid = threadIdx.x;                 // 384
  if(tid < DD){
    int base = (b*TDIM + tt)*DD;
    s3[tid] = ssum[base+tid] + ssum[base+DD+tid] + ssum[base+2*DD+tid];
    sg[tid] = sigf(w[tid]);
  }
  __syncthreads();
  int gr = (b*TDIM + tt)*NN + tid;       // window row j == feat row rowBase+j
  const float4* fr = (const float4*)(feat + (size_t)gr*DD);
  float deg = 0.f;
  #pragma unroll 8
  for(int q=0;q<DD/4;q++){
    float4 f = fr[q];
    deg += f.x*sg[q*4+0]*s3[q*4+0] + f.y*sg[q*4+1]*s3[q*4+1]
         + f.z*sg[q*4+2]*s3[q*4+2] + f.w*sg[q*4+3]*s3[q*4+3];
  }
  deg *= rscale[gr];
  dis[(size_t)bt2*W3 + tid] = (deg > 0.f) ? rsqrtf(fmaxf(deg, 1e-38f)) : 0.f;
}

// K4: per (b,tt): agg = (dis⊙GhL)·(dis⊙G)ᵀ · win ; FFN ; residual ; LayerNorm
__global__ __launch_bounds__(512) void k_main(
    const float* __restrict__ feat,
    const float* __restrict__ W1, const float* __restrict__ b1,
    const float* __restrict__ W2, const float* __restrict__ b2,
    const float* __restrict__ gamma, const float* __restrict__ beta,
    const float* __restrict__ w,
    const float* __restrict__ rscale, const float* __restrict__ dis,
    float* __restrict__ out)
{
  __shared__ float smem[128*PR + 2*32*PR + 128*PP + DD];
  float* sGhL = smem;                 // 128 x PR : scaled rows for k=2 (A of gram)
  float* sGt  = sGhL + 128*PR;        // 32 x PR  : scaled window-row tile
  float* sWt  = sGt  + 32*PR;         // 32 x PR  : raw feat window-row tile
  float* sP   = sWt  + 32*PR;         // 128 x PP : P tile
  float* sSig = sP   + 128*PP;        // 128      : sigmoid(w)
  float* sW   = sGt;                  // FFN weight staging (64 x PR == sGt+sWt)

  const int bt2 = blockIdx.x;
  const int b = bt2 / TTOUT, tt = bt2 % TTOUT;
  const int tid = threadIdx.x;
  const int rowBase = (b*TDIM + tt)*NN;     // feat row of window row 0
  const float* disP = dis + (size_t)bt2*W3;

  if(tid < DD) sSig[tid] = sigf(w[tid]);
  __syncthreads();

  // prologue: load GhL (last-N window rows, scaled)
  for(int e=tid; e<128*32; e+=512){
    int m = e>>5, d = (e&31)*4;
    int j = 256+m;
    int gr = rowBase + j;
    float4 f = *(const float4*)(feat + (size_t)gr*DD + d);
    float fac = rscale[gr]*disP[j];
    sGhL[m*PR+d+0] = f.x*sSig[d+0]*fac;
    sGhL[m*PR+d+1] = f.y*sSig[d+1]*fac;
    sGhL[m*PR+d+2] = f.z*sSig[d+2]*fac;
    sGhL[m*PR+d+3] = f.w*sSig[d+3]*fac;
  }

  const int t_d = tid & 31, t_m = tid >> 5;   // phase2/FFN layout: 16 x 32
  const int tpn = tid & 7,  tpm = tid >> 3;   // phase1 layout: 64 x 8

  float acc[8][4];
  #pragma unroll
  for(int i=0;i<8;i++){
    #pragma unroll
    for(int j=0;j<4;j++) acc[i][j]=0.f;
  }

  for(int it=0; it<12; ++it){
    const int n0 = it*32;
    __syncthreads();   // previous phase2 done before overwriting sGt/sWt
    for(int e=tid; e<32*32; e+=512){
      int r = e>>5, d = (e&31)*4;
      int j = n0 + r, gr = rowBase + j;
      float4 f = *(const float4*)(feat + (size_t)gr*DD + d);
      sWt[r*PR+d+0]=f.x; sWt[r*PR+d+1]=f.y; sWt[r*PR+d+2]=f.z; sWt[r*PR+d+3]=f.w;
      float fac = rscale[gr]*disP[j];
      sGt[r*PR+d+0]=f.x*sSig[d+0]*fac;
      sGt[r*PR+d+1]=f.y*sSig[d+1]*fac;
      sGt[r*PR+d+2]=f.z*sSig[d+2]*fac;
      sGt[r*PR+d+3]=f.w*sSig[d+3]*fac;
    }
    __syncthreads();

    // phase1: P[m][n] = GhL[m]·Gt[n], m in {tpm, tpm+64}, n in {tpn+8*jj}
    float p00=0,p01=0,p02=0,p03=0,p10=0,p11=0,p12=0,p13=0;
    #pragma unroll 4
    for(int d=0; d<DD; ++d){
      float a0 = sGhL[ tpm     *PR + d];
      float a1 = sGhL[(tpm+64) *PR + d];
      float g0 = sGt [ tpn     *PR + d];
      float g1 = sGt [(tpn+ 8) *PR + d];
      float g2 = sGt [(tpn+16) *PR + d];
      float g3 = sGt [(tpn+24) *PR + d];
      p00 += a0*g0; p01 += a0*g1; p02 += a0*g2; p03 += a0*g3;
      p10 += a1*g0; p11 += a1*g1; p12 += a1*g2; p13 += a1*g3;
    }
    sP[ tpm    *PP + tpn+ 0] = p00;
    sP[ tpm    *PP + tpn+ 8] = p01;
    sP[ tpm    *PP + tpn+16] = p02;
    sP[ tpm    *PP + tpn+24] = p03;
    sP[(tpm+64)*PP + tpn+ 0] = p10;
    sP[(tpm+64)*PP + tpn+ 8] = p11;
    sP[(tpm+64)*PP + tpn+16] = p12;
    sP[(tpm+64)*PP + tpn+24] = p13;
    __syncthreads();

    // phase2: agg[m][d] += sum_n P[m][n] * win[n][d]
    #pragma unroll 4
    for(int n=0; n<32; ++n){
      float pv[8], wv[4];
      #pragma unroll
      for(int i=0;i<8;i++) pv[i] = sP[(t_m+16*i)*PP + n];
      #pragma unroll
      for(int j=0;j<4;j++) wv[j] = sWt[n*PR + t_d + 32*j];
      #pragma unroll
      for(int i=0;i<8;i++){
        #pragma unroll
        for(int j=0;j<4;j++) acc[i][j] += pv[i]*wv[j];
      }
    }
  }

  __syncthreads();
  // agg -> LDS (reuse sGhL)
  #pragma unroll
  for(int i=0;i<8;i++){
    #pragma unroll
    for(int j=0;j<4;j++) sGhL[(t_m+16*i)*PR + t_d+32*j] = acc[i][j];
  }

  // GEMM1: h = relu(agg @ W1 + b1)
  float h[8][4];
  #pragma unroll
  for(int j=0;j<4;j++){
    float bv = b1[t_d+32*j];
    #pragma unroll
    for(int i=0;i<8;i++) h[i][j] = bv;
  }
  for(int d0=0; d0<DD; d0+=64){
    __syncthreads();
    for(int e=tid; e<64*32; e+=512){
      int r=e>>5, d=(e&31)*4;
      float4 ww = *(const float4*)(W1 + (size_t)(d0+r)*DD + d);
      sW[r*PR+d+0]=ww.x; sW[r*PR+d+1]=ww.y; sW[r*PR+d+2]=ww.z; sW[r*PR+d+3]=ww.w;
    }
    __syncthreads();
    for(int dd=0; dd<64; ++dd){
      float a[8], wv[4];
      #pragma unroll
      for(int i=0;i<8;i++) a[i] = sGhL[(t_m+16*i)*PR + d0+dd];
      #pragma unroll
      for(int j=0;j<4;j++) wv[j] = sW[dd*PR + t_d+32*j];
      #pragma unroll
      for(int i=0;i<8;i++){
        #pragma unroll
        for(int j=0;j<4;j++) h[i][j] += a[i]*wv[j];
      }
    }
  }
  #pragma unroll
  for(int i=0;i<8;i++){
    #pragma unroll
    for(int j=0;j<4;j++) h[i][j] = fmaxf(h[i][j], 0.f);
  }

  __syncthreads();   // all GEMM1 reads of sGhL done
  #pragma unroll
  for(int i=0;i<8;i++){
    #pragma unroll
    for(int j=0;j<4;j++) sGhL[(t_m+16*i)*PR + t_d+32*j] = h[i][j];
  }

  // GEMM2: o = h @ W2 + b2
  float o[8][4];
  #pragma unroll
  for(int j=0;j<4;j++){
    float bv = b2[t_d+32*j];
    #pragma unroll
    for(int i=0;i<8;i++) o[i][j] = bv;
  }
  for(int d0=0; d0<DD; d0+=64){
    __syncthreads();
    for(int e=tid; e<64*32; e+=512){
      int r=e>>5, d=(e&31)*4;
      float4 ww = *(const float4*)(W2 + (size_t)(d0+r)*DD + d);
      sW[r*PR+d+0]=ww.x; sW[r*PR+d+1]=ww.y; sW[r*PR+d+2]=ww.z; sW[r*PR+d+3]=ww.w;
    }
    __syncthreads();
    for(int dd=0; dd<64; ++dd){
      float a[8], wv[4];
      #pragma unroll
      for(int i=0;i<8;i++) a[i] = sGhL[(t_m+16*i)*PR + d0+dd];
      #pragma unroll
      for(int j=0;j<4;j++) wv[j] = sW[dd*PR + t_d+32*j];
      #pragma unroll
      for(int i=0;i<8;i++){
        #pragma unroll
        for(int j=0;j<4;j++) o[i][j] += a[i]*wv[j];
      }
    }
  }

  // residual + LayerNorm
  float sum[8], sumsq[8];
  #pragma unroll
  for(int i=0;i<8;i++){
    sum[i]=0.f; sumsq[i]=0.f;
    int gr = rowBase + 256 + (t_m+16*i);           // feat row (b, tt+2, m)
    #pragma unroll
    for(int j=0;j<4;j++){
      float s = o[i][j] + feat[(size_t)gr*DD + t_d+32*j];
      o[i][j] = s;
      sum[i] += s; sumsq[i] += s*s;
    }
  }
  #pragma unroll
  for(int i=0;i<8;i++){
    #pragma unroll
    for(int k=1;k<32;k<<=1){
      sum[i]   += __shfl_xor(sum[i], k);
      sumsq[i] += __shfl_xor(sumsq[i], k);
    }
  }
  #pragma unroll
  for(int i=0;i<8;i++){
    float mu  = sum[i] * (1.0f/DD);
    float var = sumsq[i] * (1.0f/DD) - mu*mu;
    float rstd = rsqrtf(var + 1e-5f);
    int m = t_m + 16*i;
    #pragma unroll
    for(int j=0;j<4;j++){
      int c = t_d + 32*j;
      out[((size_t)bt2*NN + m)*DD + c] = (o[i][j]-mu)*rstd*gamma[c] + beta[c];
    }
  }
}

extern "C" void kernel_launch(void* const* d_in, const int* in_sizes, int n_in,
                              void* d_out, int out_size, void* d_ws, size_t ws_size,
                              hipStream_t stream){
  const float* feat  = (const float*)d_in[0];
  const float* w     = (const float*)d_in[1];
  const float* W1    = (const float*)d_in[2];
  const float* b1    = (const float*)d_in[3];
  const float* W2    = (const float*)d_in[4];
  const float* b2    = (const float*)d_in[5];
  const float* gamma = (const float*)d_in[6];
  const float* beta  = (const float*)d_in[7];
  float* out = (float*)d_out;

  float* rscale = (float*)d_ws;                 // B*T*N   = 65536 floats
  float* ssum   = rscale + BB*TDIM*NN;          // B*T*D   = 65536 floats
  float* dis    = ssum   + BB*TDIM*DD;          // B*(T-2)*384 = 190464 floats

  k_rscale<<<BB*TDIM*NN/4, 256, 0, stream>>>(feat, w, rscale);
  k_ssum  <<<BB*TDIM,      128, 0, stream>>>(feat, w, rscale, ssum);
  k_dis   <<<BB*TTOUT,     W3,  0, stream>>>(feat, w, rscale, ssum, dis);
  k_main  <<<BB*TTOUT,     512, 0, stream>>>(feat, W1, b1, W2, b2, gamma, beta, w,
                                             rscale, dis, out);
}

// Round 2
// 90.922 us; speedup vs baseline: 3.9983x; 3.9983x over previous
//
#include <hip/hip_runtime.h>
#include <math.h>

#define BB    8
#define TDIM  64
#define NN    128
#define DD    128
#define TTOUT 62      // T-2
#define W3    384     // 3*N
#define LG    136     // row stride (ushort) for 128-wide bf16 tiles (272B: 2-way-free frag reads)
#define LP    40      // row stride for 32-wide bf16 tiles (80B)
#define LW    72      // row stride for 64-wide bf16 tiles (144B)

typedef __attribute__((ext_vector_type(8))) short bf16x8;
typedef __attribute__((ext_vector_type(4))) float f32x4;

__device__ __forceinline__ float sigf(float x){ return 1.0f/(1.0f+__expf(-x)); }
__device__ __forceinline__ unsigned short f2bf(float x){
  union{float f; unsigned u;} v; v.f=x;
  unsigned r = v.u + 0x7FFFu + ((v.u>>16)&1u);   // RNE
  return (unsigned short)(r>>16);
}

// K1: rscale[b,t,n] = 1 / max(||feat[b,t,n,:]*sigmoid(w)||, 1e-12)
__global__ void k_rscale(const float* __restrict__ feat, const float* __restrict__ w,
                         float* __restrict__ rscale){
  int row  = blockIdx.x*4 + (threadIdx.x>>6);
  int lane = threadIdx.x & 63;
  float2 f  = *(const float2*)(feat + (size_t)row*DD + lane*2);
  float2 wv = *(const float2*)(w + lane*2);
  float v0 = f.x * sigf(wv.x);
  float v1 = f.y * sigf(wv.y);
  float ss = v0*v0 + v1*v1;
  #pragma unroll
  for(int k=32;k>=1;k>>=1) ss += __shfl_xor(ss, k);
  if(lane==0) rscale[row] = 1.0f / fmaxf(sqrtf(ss), 1e-12f);
}

// K2: ssum[b,t,d] = sig(w[d]) * sum_n feat[b,t,n,d]*rscale[b,t,n]
__global__ void k_ssum(const float* __restrict__ feat, const float* __restrict__ w,
                       const float* __restrict__ rscale, float* __restrict__ ssum){
  int bt = blockIdx.x;
  int d  = threadIdx.x;
  const float* fp = feat + (size_t)bt*NN*DD + d;
  const float* rp = rscale + bt*NN;
  float acc = 0.f;
  #pragma unroll 4
  for(int n=0;n<NN;n++) acc += fp[(size_t)n*DD] * rp[n];
  ssum[bt*DD + d] = acc * sigf(w[d]);
}

// K3: dis[b,tt,j] = deg>0 ? rsqrt(max(deg,1e-38)) : 0
__global__ void k_dis(const float* __restrict__ feat, const float* __restrict__ w,
                      const float* __restrict__ rscale, const float* __restrict__ ssum,
                      float* __restrict__ dis){
  __shared__ float s3[DD];
  __shared__ float sg[DD];
  int bt2 = blockIdx.x;
  int b = bt2 / TTOUT, tt = bt2 % TTOUT;
  int tid = threadIdx.x;
  if(tid < DD){
    int base = (b*TDIM + tt)*DD;
    s3[tid] = ssum[base+tid] + ssum[base+DD+tid] + ssum[base+2*DD+tid];
    sg[tid] = sigf(w[tid]);
  }
  __syncthreads();
  int gr = (b*TDIM + tt)*NN + tid;
  const float4* fr = (const float4*)(feat + (size_t)gr*DD);
  float deg = 0.f;
  #pragma unroll 8
  for(int q=0;q<DD/4;q++){
    float4 f = fr[q];
    deg += f.x*sg[q*4+0]*s3[q*4+0] + f.y*sg[q*4+1]*s3[q*4+1]
         + f.z*sg[q*4+2]*s3[q*4+2] + f.w*sg[q*4+3]*s3[q*4+3];
  }
  deg *= rscale[gr];
  dis[(size_t)bt2*W3 + tid] = (deg > 0.f) ? rsqrtf(fmaxf(deg, 1e-38f)) : 0.f;
}

// K4: per (b,tt): P = GhL·Gᵀ (MFMA), agg = P·win (MFMA), FFN (MFMA), residual+LN
__global__ __launch_bounds__(512,4) void k_main(
    const float* __restrict__ feat,
    const float* __restrict__ W1, const float* __restrict__ b1,
    const float* __restrict__ W2, const float* __restrict__ b2,
    const float* __restrict__ gamma, const float* __restrict__ beta,
    const float* __restrict__ w,
    const float* __restrict__ rscale, const float* __restrict__ dis,
    float* __restrict__ out)
{
  __shared__ __align__(16) unsigned short sm[32000];   // 64 KB
  __shared__ float sSig[DD];
  unsigned short* sA  = sm;            // 128 x LG : scaled GhL bf16; later agg, then h
  unsigned short* sG  = sm + 17408;    // 32 x LG  : scaled window tile
  unsigned short* sFt = sm + 21760;    // 128 x LP : raw window tile, transposed [d][n]
  unsigned short* sP  = sm + 26880;    // 128 x LP : P chunk bf16
  unsigned short* sWt = sm + 17408;    // 128 x LW : FFN weights transposed (overlays sG+sFt)

  const int bt2 = blockIdx.x;
  const int tid = threadIdx.x;
  const int rowBase = (bt2/TTOUT)*TDIM*NN + (bt2%TTOUT)*NN;
  const float* disP = dis + (size_t)bt2*W3;

  const int lane = tid & 63, wid = tid >> 6;
  const int l15 = lane & 15, l4 = lane >> 4;
  const int m0 = wid * 16;                      // this wave's 16-row M-strip

  if(tid < DD) sSig[tid] = sigf(w[tid]);
  __syncthreads();

  // prologue: sA = scaled GhL (window rows 256..383) in bf16
  #pragma unroll
  for(int e0=0; e0<8; ++e0){
    int e = e0*512 + tid;            // 4096 elems-of-4
    int d = e & 127, r0 = (e>>7)*4;
    float sg = sSig[d];
    #pragma unroll
    for(int i=0;i<4;i++){
      int j = 256 + r0 + i, gr = rowBase + j;
      float f = feat[(size_t)gr*DD + d];
      float fac = rscale[gr]*disP[j];
      sA[(r0+i)*LG + d] = f2bf(f*sg*fac);
    }
  }

  f32x4 acc2[8];
  #pragma unroll
  for(int i=0;i<8;i++) acc2[i] = (f32x4){0.f,0.f,0.f,0.f};

  for(int c=0; c<12; ++c){
    const int n0 = c*32;
    __syncthreads();   // prev phase2 done with sG/sFt/sP
    // stage sG (scaled bf16, row-major) + sFt (raw bf16, transposed)
    #pragma unroll
    for(int e0=0; e0<2; ++e0){
      int e = e0*512 + tid;          // 1024
      int d = e & 127, r0 = (e>>7)*4;
      float sg = sSig[d];
      unsigned short fb[4];
      #pragma unroll
      for(int i=0;i<4;i++){
        int j = n0 + r0 + i, gr = rowBase + j;
        float f = feat[(size_t)gr*DD + d];
        float fac = rscale[gr]*disP[j];
        fb[i] = f2bf(f);
        sG[(r0+i)*LG + d] = f2bf(f*sg*fac);
      }
      unsigned int* fp = (unsigned int*)&sFt[d*LP + r0];
      fp[0] = (unsigned)fb[0] | ((unsigned)fb[1]<<16);
      fp[1] = (unsigned)fb[2] | ((unsigned)fb[3]<<16);
    }
    __syncthreads();

    // phase1: P[:, n0:n0+32] = GhL(128xK=128) x Gtile^T
    f32x4 p0 = {0.f,0.f,0.f,0.f}, p1 = {0.f,0.f,0.f,0.f};
    #pragma unroll
    for(int ks=0; ks<4; ++ks){
      bf16x8 aA  = *(const bf16x8*)&sA[(m0+l15)*LG + ks*32 + l4*8];
      bf16x8 bg0 = *(const bf16x8*)&sG[( 0+l15)*LG + ks*32 + l4*8];
      bf16x8 bg1 = *(const bf16x8*)&sG[(16+l15)*LG + ks*32 + l4*8];
      p0 = __builtin_amdgcn_mfma_f32_16x16x32_bf16(aA, bg0, p0, 0,0,0);
      p1 = __builtin_amdgcn_mfma_f32_16x16x32_bf16(aA, bg1, p1, 0,0,0);
    }
    #pragma unroll
    for(int r=0;r<4;r++){
      sP[(m0 + l4*4 + r)*LP +  0 + l15] = f2bf(p0[r]);
      sP[(m0 + l4*4 + r)*LP + 16 + l15] = f2bf(p1[r]);
    }
    __syncthreads();

    // phase2: agg += P(128x32) x F(32x128)  [B-frag from transposed sFt]
    bf16x8 aP = *(const bf16x8*)&sP[(m0+l15)*LP + l4*8];
    #pragma unroll
    for(int dt=0; dt<8; ++dt){
      bf16x8 bF = *(const bf16x8*)&sFt[(dt*16+l15)*LP + l4*8];
      acc2[dt] = __builtin_amdgcn_mfma_f32_16x16x32_bf16(aP, bF, acc2[dt], 0,0,0);
    }
  }

  // agg -> sA (bf16); strip-local (D-frag rows == own M-strip)
  #pragma unroll
  for(int dt=0; dt<8; ++dt)
    #pragma unroll
    for(int r=0;r<4;r++)
      sA[(m0+l4*4+r)*LG + dt*16+l15] = f2bf(acc2[dt][r]);

  // GEMM1: h = relu(agg @ W1 + b1)
  f32x4 acch[8];
  #pragma unroll
  for(int dt=0; dt<8; ++dt){
    float bv = b1[dt*16+l15];
    acch[dt] = (f32x4){bv,bv,bv,bv};
  }
  for(int kh=0; kh<2; ++kh){
    __syncthreads();   // all reads of sG/sFt (or prev sWt) done
    #pragma unroll
    for(int e0=0; e0<4; ++e0){
      int e = e0*512+tid;            // 2048
      int n = e&127, k0 = (e>>7)*4;
      float w0 = W1[(size_t)(kh*64+k0+0)*DD + n];
      float w1v= W1[(size_t)(kh*64+k0+1)*DD + n];
      float w2v= W1[(size_t)(kh*64+k0+2)*DD + n];
      float w3v= W1[(size_t)(kh*64+k0+3)*DD + n];
      unsigned int* wp = (unsigned int*)&sWt[n*LW + k0];
      wp[0] = (unsigned)f2bf(w0) | ((unsigned)f2bf(w1v)<<16);
      wp[1] = (unsigned)f2bf(w2v)| ((unsigned)f2bf(w3v)<<16);
    }
    __syncthreads();
    #pragma unroll
    for(int ks=0; ks<2; ++ks){
      bf16x8 aA = *(const bf16x8*)&sA[(m0+l15)*LG + kh*64 + ks*32 + l4*8];
      #pragma unroll
      for(int dt=0; dt<8; ++dt){
        bf16x8 bW = *(const bf16x8*)&sWt[(dt*16+l15)*LW + ks*32 + l4*8];
        acch[dt] = __builtin_amdgcn_mfma_f32_16x16x32_bf16(aA, bW, acch[dt], 0,0,0);
      }
    }
  }
  __syncthreads();
  // h -> sA (strip-local)
  #pragma unroll
  for(int dt=0; dt<8; ++dt)
    #pragma unroll
    for(int r=0;r<4;r++)
      sA[(m0+l4*4+r)*LG + dt*16+l15] = f2bf(fmaxf(acch[dt][r], 0.f));

  // GEMM2: o = h @ W2 + b2
  f32x4 acco[8];
  #pragma unroll
  for(int dt=0; dt<8; ++dt){
    float bv = b2[dt*16+l15];
    acco[dt] = (f32x4){bv,bv,bv,bv};
  }
  for(int kh=0; kh<2; ++kh){
    __syncthreads();
    #pragma unroll
    for(int e0=0; e0<4; ++e0){
      int e = e0*512+tid;
      int n = e&127, k0 = (e>>7)*4;
      float w0 = W2[(size_t)(kh*64+k0+0)*DD + n];
      float w1v= W2[(size_t)(kh*64+k0+1)*DD + n];
      float w2v= W2[(size_t)(kh*64+k0+2)*DD + n];
      float w3v= W2[(size_t)(kh*64+k0+3)*DD + n];
      unsigned int* wp = (unsigned int*)&sWt[n*LW + k0];
      wp[0] = (unsigned)f2bf(w0) | ((unsigned)f2bf(w1v)<<16);
      wp[1] = (unsigned)f2bf(w2v)| ((unsigned)f2bf(w3v)<<16);
    }
    __syncthreads();
    #pragma unroll
    for(int ks=0; ks<2; ++ks){
      bf16x8 aA = *(const bf16x8*)&sA[(m0+l15)*LG + kh*64 + ks*32 + l4*8];
      #pragma unroll
      for(int dt=0; dt<8; ++dt){
        bf16x8 bW = *(const bf16x8*)&sWt[(dt*16+l15)*LW + ks*32 + l4*8];
        acco[dt] = __builtin_amdgcn_mfma_f32_16x16x32_bf16(aA, bW, acco[dt], 0,0,0);
      }
    }
  }

  // residual + LayerNorm (fp32). Row m lives in one 16-lane group, regs over dt.
  const float* fres = feat + (size_t)(rowBase + 256)*DD;
  #pragma unroll
  for(int r=0;r<4;r++){
    int m = m0 + l4*4 + r;
    float vals[8]; float s1 = 0.f, s2 = 0.f;
    #pragma unroll
    for(int dt=0; dt<8; ++dt){
      int d = dt*16 + l15;
      float v = acco[dt][r] + fres[(size_t)m*DD + d];
      vals[dt] = v; s1 += v; s2 += v*v;
    }
    #pragma unroll
    for(int k=1;k<16;k<<=1){ s1 += __shfl_xor(s1,k); s2 += __shfl_xor(s2,k); }
    float mu   = s1*(1.0f/DD);
    float rstd = rsqrtf(s2*(1.0f/DD) - mu*mu + 1e-5f);
    #pragma unroll
    for(int dt=0; dt<8; ++dt){
      int d = dt*16 + l15;
      out[((size_t)bt2*NN + m)*DD + d] = (vals[dt]-mu)*rstd*gamma[d] + beta[d];
    }
  }
}

extern "C" void kernel_launch(void* const* d_in, const int* in_sizes, int n_in,
                              void* d_out, int out_size, void* d_ws, size_t ws_size,
                              hipStream_t stream){
  const float* feat  = (const float*)d_in[0];
  const float* w     = (const float*)d_in[1];
  const float* W1    = (const float*)d_in[2];
  const float* b1    = (const float*)d_in[3];
  const float* W2    = (const float*)d_in[4];
  const float* b2    = (const float*)d_in[5];
  const float* gamma = (const float*)d_in[6];
  const float* beta  = (const float*)d_in[7];
  float* out = (float*)d_out;

  float* rscale = (float*)d_ws;                 // B*T*N
  float* ssum   = rscale + BB*TDIM*NN;          // B*T*D
  float* dis    = ssum   + BB*TDIM*DD;          // B*(T-2)*384

  k_rscale<<<BB*TDIM*NN/4, 256, 0, stream>>>(feat, w, rscale);
  k_ssum  <<<BB*TDIM,      128, 0, stream>>>(feat, w, rscale, ssum);
  k_dis   <<<BB*TTOUT,     W3,  0, stream>>>(feat, w, rscale, ssum, dis);
  k_main  <<<BB*TTOUT,     512, 0, stream>>>(feat, W1, b1, W2, b2, gamma, beta, w,
                                             rscale, dis, out);
}